// Round 5
// baseline (424.754 us; speedup 1.0000x reference)
//
#include <hip/hip_runtime.h>
#include <math.h>

// GCN 5-layer: per layer relu(A @ (h @ W) + b), A = sym-normalized adj w/ self-loops.
// CSR-by-dst build, aggregate on the narrow side of each GEMM, fold dinv[src]
// row-scaling into GEMM epilogues. All fp32.
// R2: hierarchical scan. R3: binned fill (FAILED, 80MB write amp).
// R4: radix build (bins of 512 dsts, single-ownership writes) — build ~50us.
// R5: float4 multi-edge-group aggregation (16 lanes/row for W=64 -> 4 edges in
//     flight per wave-instr, shfl_xor cross-group combine); gemm5 fused into
//     W=16 agg epilogue (h4 never materialized).

#define NBIN_MAX 256
#define BSHIFT 9
#define BINW 512
#define CHUNK 8192

// ---------------- graph build (R4 radix pipeline) ----------------
__global__ __launch_bounds__(256) void k_hist(const int* __restrict__ dst, int E,
                                              int nbin, int* __restrict__ binCnt) {
    __shared__ int h[NBIN_MAX];
    int t = threadIdx.x;
    for (int i = t; i < nbin; i += 256) h[i] = 0;
    __syncthreads();
    for (int e = blockIdx.x * 256 + t; e < E; e += gridDim.x * 256)
        atomicAdd(&h[dst[e] >> BSHIFT], 1);
    __syncthreads();
    for (int i = t; i < nbin; i += 256)
        if (h[i]) atomicAdd(&binCnt[i], h[i]);
}

__global__ __launch_bounds__(256) void k_binscan(const int* __restrict__ binCnt,
                                                 int nbin, int* __restrict__ binBase,
                                                 int* __restrict__ binCur) {
    __shared__ int sh[256];
    int t = threadIdx.x;
    int v = (t < nbin) ? binCnt[t] : 0;
    sh[t] = v;
    __syncthreads();
    for (int d = 1; d < 256; d <<= 1) {
        int u = (t >= d) ? sh[t - d] : 0;
        __syncthreads();
        sh[t] += u;
        __syncthreads();
    }
    int ex = sh[t] - v;
    if (t < nbin) { binBase[t] = ex; binCur[t] = ex; }
    if (t == nbin - 1) binBase[nbin] = sh[t];
}

__global__ __launch_bounds__(256) void k_binfill(const int* __restrict__ src,
                                                 const int* __restrict__ dst, int E,
                                                 int nbin, int* __restrict__ binCur,
                                                 unsigned* __restrict__ tmp) {
    __shared__ int h[NBIN_MAX];
    __shared__ int res[NBIN_MAX];
    int t = threadIdx.x;
    int e0 = blockIdx.x * CHUNK;
    int e1 = min(e0 + CHUNK, E);
    for (int i = t; i < nbin; i += 256) h[i] = 0;
    __syncthreads();
    for (int e = e0 + t; e < e1; e += 256)
        atomicAdd(&h[dst[e] >> BSHIFT], 1);
    __syncthreads();
    for (int i = t; i < nbin; i += 256)
        res[i] = h[i] ? atomicAdd(&binCur[i], h[i]) : 0;
    __syncthreads();
    for (int i = t; i < nbin; i += 256) h[i] = 0;
    __syncthreads();
    for (int e = e0 + t; e < e1; e += 256) {
        int d = dst[e];
        int b = d >> BSHIFT;
        int p = res[b] + atomicAdd(&h[b], 1);
        tmp[p] = ((unsigned)src[e] << BSHIFT) | (unsigned)(d & (BINW - 1));
    }
}

__global__ __launch_bounds__(256) void k_csr(const unsigned* __restrict__ tmp,
                                             const int* __restrict__ binBase,
                                             int n, int nbin,
                                             float* __restrict__ dinv,
                                             int* __restrict__ offs,
                                             int* __restrict__ csr) {
    __shared__ int ldeg[BINW];
    __shared__ int loff[BINW];
    __shared__ int pair[256];
    int b = blockIdx.x;
    int t = threadIdx.x;
    ldeg[t] = 0; ldeg[t + 256] = 0;
    __syncthreads();
    int lo = binBase[b], hi = binBase[b + 1];
    for (int p = lo + t; p < hi; p += 256)
        atomicAdd(&ldeg[tmp[p] & (BINW - 1u)], 1);
    __syncthreads();
    int a0 = ldeg[2 * t], a1 = ldeg[2 * t + 1];
    pair[t] = a0 + a1;
    __syncthreads();
    int v = pair[t];
    for (int d = 1; d < 256; d <<= 1) {
        int u = (t >= d) ? pair[t - d] : 0;
        __syncthreads();
        pair[t] += u;
        __syncthreads();
    }
    int ex = pair[t] - v;
    loff[2 * t] = ex;
    loff[2 * t + 1] = ex + a0;
    __syncthreads();
    int v0 = b << BSHIFT;
    for (int i = t; i < BINW; i += 256) {
        int vv = v0 + i;
        if (vv < n) {
            offs[vv] = lo + loff[i];
            dinv[vv] = 1.0f / sqrtf((float)(ldeg[i] + 1));
        }
    }
    if (t == 0 && b == nbin - 1) offs[n] = hi;
    __syncthreads();
    ldeg[t] = 0; ldeg[t + 256] = 0;
    __syncthreads();
    for (int p = lo + t; p < hi; p += 256) {
        unsigned u = tmp[p];
        int d0 = (int)(u & (BINW - 1u));
        int pos = loff[d0] + atomicAdd(&ldeg[d0], 1);
        csr[lo + pos] = (int)(u >> BSHIFT);
    }
}

// ---------------- aggregation (R5: float4 lanes, multi-edge groups) ----------------
// One wave per dst row. LPR = W/4 lanes cover the row with float4 loads;
// G = 64/LPR edges processed per step; 2x unrolled; shfl_xor combine.
// L1SCALE: gather x[u]*dinv[u] (layer 1).  Else S is pre-scaled.
// out[v] = act(dinv[v]*(sum + self) + bias)
template <int W, bool RELU, bool BIAS, bool L1SCALE>
__global__ __launch_bounds__(256) void k_aggv(const float* __restrict__ S,
                                              const float* __restrict__ dinv,
                                              const int* __restrict__ offs,
                                              const int* __restrict__ csr,
                                              const float* __restrict__ bg,
                                              float* __restrict__ Y, int n) {
    constexpr int LPR = W / 4;
    constexpr int G = 64 / LPR;
    int lane = threadIdx.x & 63;
    int wave = threadIdx.x >> 6;
    int v = blockIdx.x * 4 + wave;
    if (v >= n) return;
    int g = lane / LPR;
    int j = lane % LPR;
    float dv = dinv[v];
    float4 acc0 = make_float4(0.f, 0.f, 0.f, 0.f);
    float4 acc1 = make_float4(0.f, 0.f, 0.f, 0.f);
    if (g == 0) {  // self-loop term
        float4 xv = *(const float4*)&S[(size_t)v * W + j * 4];
        float sc = L1SCALE ? dv : 1.0f;
        acc0.x = xv.x * sc; acc0.y = xv.y * sc; acc0.z = xv.z * sc; acc0.w = xv.w * sc;
    }
    int e0 = offs[v], re = offs[v + 1];
    for (int eb = e0; eb < re; eb += 2 * G) {
        int ea = eb + g, ec = eb + G + g;
        if (ea < re) {
            int u = csr[ea];
            float4 a = *(const float4*)&S[(size_t)u * W + j * 4];
            float sc = L1SCALE ? dinv[u] : 1.0f;
            acc0.x += a.x * sc; acc0.y += a.y * sc; acc0.z += a.z * sc; acc0.w += a.w * sc;
        }
        if (ec < re) {
            int u = csr[ec];
            float4 a = *(const float4*)&S[(size_t)u * W + j * 4];
            float sc = L1SCALE ? dinv[u] : 1.0f;
            acc1.x += a.x * sc; acc1.y += a.y * sc; acc1.z += a.z * sc; acc1.w += a.w * sc;
        }
    }
    acc0.x += acc1.x; acc0.y += acc1.y; acc0.z += acc1.z; acc0.w += acc1.w;
#pragma unroll
    for (int d = LPR; d < 64; d <<= 1) {
        acc0.x += __shfl_xor(acc0.x, d);
        acc0.y += __shfl_xor(acc0.y, d);
        acc0.z += __shfl_xor(acc0.z, d);
        acc0.w += __shfl_xor(acc0.w, d);
    }
    if (lane < LPR) {
        float4 r;
        r.x = dv * acc0.x; r.y = dv * acc0.y; r.z = dv * acc0.z; r.w = dv * acc0.w;
        if (BIAS) {
            float4 bv = *(const float4*)&bg[j * 4];
            r.x += bv.x; r.y += bv.y; r.z += bv.z; r.w += bv.w;
        }
        if (RELU) {
            r.x = fmaxf(r.x, 0.f); r.y = fmaxf(r.y, 0.f);
            r.z = fmaxf(r.z, 0.f); r.w = fmaxf(r.w, 0.f);
        }
        *(float4*)&Y[(size_t)v * W + j * 4] = r;
    }
}

// W=16 aggregation with gemm5 fused: h4 = relu(dinv[v]*sum + b4) (never stored);
// Y[v] = (h4 . W5) * dinv[v]
__global__ __launch_bounds__(256) void k_agg16_gemm5(const float* __restrict__ S,
                                                     const float* __restrict__ dinv,
                                                     const int* __restrict__ offs,
                                                     const int* __restrict__ csr,
                                                     const float* __restrict__ b4,
                                                     const float* __restrict__ W5,
                                                     float* __restrict__ Y, int n) {
    constexpr int W = 16, LPR = 4, G = 16;
    int lane = threadIdx.x & 63;
    int wave = threadIdx.x >> 6;
    int v = blockIdx.x * 4 + wave;
    if (v >= n) return;
    int g = lane / LPR;
    int j = lane % LPR;
    float dv = dinv[v];
    float4 acc0 = make_float4(0.f, 0.f, 0.f, 0.f);
    float4 acc1 = make_float4(0.f, 0.f, 0.f, 0.f);
    if (g == 0) acc0 = *(const float4*)&S[(size_t)v * W + j * 4];
    int e0 = offs[v], re = offs[v + 1];
    for (int eb = e0; eb < re; eb += 2 * G) {
        int ea = eb + g, ec = eb + G + g;
        if (ea < re) {
            int u = csr[ea];
            float4 a = *(const float4*)&S[(size_t)u * W + j * 4];
            acc0.x += a.x; acc0.y += a.y; acc0.z += a.z; acc0.w += a.w;
        }
        if (ec < re) {
            int u = csr[ec];
            float4 a = *(const float4*)&S[(size_t)u * W + j * 4];
            acc1.x += a.x; acc1.y += a.y; acc1.z += a.z; acc1.w += a.w;
        }
    }
    acc0.x += acc1.x; acc0.y += acc1.y; acc0.z += acc1.z; acc0.w += acc1.w;
#pragma unroll
    for (int d = LPR; d < 64; d <<= 1) {
        acc0.x += __shfl_xor(acc0.x, d);
        acc0.y += __shfl_xor(acc0.y, d);
        acc0.z += __shfl_xor(acc0.z, d);
        acc0.w += __shfl_xor(acc0.w, d);
    }
    // h4 slice (cols j*4..j*4+3) in every lane group; dot with W5 and reduce 4 lanes
    float4 bv = *(const float4*)&b4[j * 4];
    float4 w5 = *(const float4*)&W5[j * 4];
    float hx = fmaxf(dv * acc0.x + bv.x, 0.f);
    float hy = fmaxf(dv * acc0.y + bv.y, 0.f);
    float hz = fmaxf(dv * acc0.z + bv.z, 0.f);
    float hw = fmaxf(dv * acc0.w + bv.w, 0.f);
    float p = hx * w5.x + hy * w5.y + hz * w5.z + hw * w5.w;
    p += __shfl_xor(p, 1);
    p += __shfl_xor(p, 2);
    if (lane == 0) Y[v] = p * dv;
}

// Final W=1 aggregation: out[v] = dinv[v]*(sum_u s5[u] + s5[v]) + b5 (no relu)
__global__ __launch_bounds__(256) void k_agg1(const float* __restrict__ S,
                                              const float* __restrict__ dinv,
                                              const int* __restrict__ offs,
                                              const int* __restrict__ csr,
                                              const float* __restrict__ bg,
                                              float* __restrict__ Y, int n) {
    int v = blockIdx.x * 256 + threadIdx.x;
    if (v >= n) return;
    float sum = S[v];
    int e = offs[v], re = offs[v + 1];
    for (; e < re; ++e) sum += S[csr[e]];
    Y[v] = dinv[v] * sum + bg[0];
}

// ---------------- tall-skinny GEMMs ----------------
template <int IN, int OUT, int EPI>
__global__ __launch_bounds__(256) void k_gemm(const float* __restrict__ X,
                                              const float* __restrict__ Wg,
                                              const float* __restrict__ bg,
                                              const float* __restrict__ dinv,
                                              float* __restrict__ Y, int nrows) {
    constexpr int TPR = OUT / 4;
    constexpr int GROUPS = 256 / TPR;
    constexpr int ROWS = GROUPS * 2;
    __shared__ __align__(16) float Wl[IN * OUT];
    __shared__ __align__(16) float xl[ROWS * IN];
    __shared__ float bl[OUT];
    int tid = threadIdx.x;
    for (int i = tid; i < IN * OUT; i += 256) Wl[i] = Wg[i];
    if (EPI == 0)
        for (int i = tid; i < OUT; i += 256) bl[i] = bg[i];
    int base = blockIdx.x * ROWS;
    for (int i = tid; i < ROWS * IN; i += 256) {
        int r = base + i / IN;
        xl[i] = (r < nrows) ? X[(size_t)base * IN + i] : 0.0f;
    }
    __syncthreads();
    int g = tid / TPR;
    int c0 = (tid % TPR) * 4;
    int r0 = base + g * 2, r1 = r0 + 1;
    int l0 = (g * 2) * IN, l1 = l0 + IN;
    float4 acc0 = make_float4(0.f, 0.f, 0.f, 0.f);
    float4 acc1 = make_float4(0.f, 0.f, 0.f, 0.f);
#pragma unroll 8
    for (int k = 0; k < IN; ++k) {
        float4 w = *(const float4*)&Wl[k * OUT + c0];
        float a0 = xl[l0 + k], a1 = xl[l1 + k];
        acc0.x += a0 * w.x; acc0.y += a0 * w.y; acc0.z += a0 * w.z; acc0.w += a0 * w.w;
        acc1.x += a1 * w.x; acc1.y += a1 * w.y; acc1.z += a1 * w.z; acc1.w += a1 * w.w;
    }
    if (EPI == 0) {
        float bx = bl[c0], by = bl[c0 + 1], bz = bl[c0 + 2], bw = bl[c0 + 3];
        acc0.x = fmaxf(acc0.x + bx, 0.f); acc0.y = fmaxf(acc0.y + by, 0.f);
        acc0.z = fmaxf(acc0.z + bz, 0.f); acc0.w = fmaxf(acc0.w + bw, 0.f);
        acc1.x = fmaxf(acc1.x + bx, 0.f); acc1.y = fmaxf(acc1.y + by, 0.f);
        acc1.z = fmaxf(acc1.z + bz, 0.f); acc1.w = fmaxf(acc1.w + bw, 0.f);
    } else {
        if (r0 < nrows) { float d0 = dinv[r0]; acc0.x *= d0; acc0.y *= d0; acc0.z *= d0; acc0.w *= d0; }
        if (r1 < nrows) { float d1 = dinv[r1]; acc1.x *= d1; acc1.y *= d1; acc1.z *= d1; acc1.w *= d1; }
    }
    if (r0 < nrows) *(float4*)&Y[(size_t)r0 * OUT + c0] = acc0;
    if (r1 < nrows) *(float4*)&Y[(size_t)r1 * OUT + c0] = acc1;
}

extern "C" void kernel_launch(void* const* d_in, const int* in_sizes, int n_in,
                              void* d_out, int out_size, void* d_ws, size_t ws_size,
                              hipStream_t stream) {
    const float* x  = (const float*)d_in[0];
    const int*   ei = (const int*)d_in[1];
    const float* W1 = (const float*)d_in[2];  const float* b1 = (const float*)d_in[3];
    const float* W2 = (const float*)d_in[4];  const float* b2 = (const float*)d_in[5];
    const float* W3 = (const float*)d_in[6];  const float* b3 = (const float*)d_in[7];
    const float* W4 = (const float*)d_in[8];  const float* b4 = (const float*)d_in[9];
    const float* W5 = (const float*)d_in[10]; const float* b5 = (const float*)d_in[11];

    const int N = in_sizes[0] / 64;   // 100000
    const int E = in_sizes[1] / 2;    // 1600000
    const int* src = ei;
    const int* dst = ei + E;
    const int nbin = (N + BINW - 1) / BINW;   // 196

    char* ws = (char*)d_ws;
    size_t off = 0;
    auto alloc = [&](size_t bytes) -> void* {
        void* p = ws + off;
        off = (off + bytes + 255) & ~(size_t)255;
        return p;
    };
    float* dinv    = (float*)alloc((size_t)N * 4);
    int*   offs    = (int*)alloc((size_t)(N + 1) * 4);
    int*   binCnt  = (int*)alloc((size_t)NBIN_MAX * 4);
    int*   binBase = (int*)alloc((size_t)(NBIN_MAX + 1) * 4);
    int*   binCur  = (int*)alloc((size_t)NBIN_MAX * 4);
    int*   csr     = (int*)alloc((size_t)E * 4);
    float* s5      = (float*)alloc((size_t)N * 4);
    float* A       = (float*)alloc((size_t)N * 128 * 4);  // h1 / h3
    float* B       = (float*)alloc((size_t)N * 64 * 4);   // agg1/s2/s3/s4
    float* C       = (float*)alloc((size_t)N * 64 * 4);   // h2; aliased as tmp
    unsigned* tmp  = (unsigned*)C;

    hipMemsetAsync(binCnt, 0, (size_t)NBIN_MAX * 4, stream);

    k_hist<<<256, 256, 0, stream>>>(dst, E, nbin, binCnt);
    k_binscan<<<1, 256, 0, stream>>>(binCnt, nbin, binBase, binCur);
    k_binfill<<<(E + CHUNK - 1) / CHUNK, 256, 0, stream>>>(src, dst, E, nbin, binCur, tmp);
    k_csr<<<nbin, 256, 0, stream>>>(tmp, binBase, N, nbin, dinv, offs, csr);

    const int gagg = (N + 3) / 4;
    // Layer 1: agg1 = A.x (64 wide, dinv fused), then h1 = relu(agg1 @ W1 + b1)
    k_aggv<64, false, false, true><<<gagg, 256, 0, stream>>>(x, dinv, offs, csr, nullptr, B, N);
    k_gemm<64, 128, 0><<<(N + 15) / 16, 256, 0, stream>>>(B, W1, b1, nullptr, A, N);
    // Layer 2
    k_gemm<128, 64, 1><<<(N + 31) / 32, 256, 0, stream>>>(A, W2, nullptr, dinv, B, N);
    k_aggv<64, true, true, false><<<gagg, 256, 0, stream>>>(B, dinv, offs, csr, b2, C, N);
    // Layer 3
    k_gemm<64, 32, 1><<<(N + 63) / 64, 256, 0, stream>>>(C, W3, nullptr, dinv, B, N);
    k_aggv<32, true, true, false><<<gagg, 256, 0, stream>>>(B, dinv, offs, csr, b3, A, N);
    // Layer 4: s4 = (h3 @ W4)*dinv, then fused agg+gemm5 -> s5 (h4 never stored)
    k_gemm<32, 16, 1><<<(N + 127) / 128, 256, 0, stream>>>(A, W4, nullptr, dinv, B, N);
    k_agg16_gemm5<<<gagg, 256, 0, stream>>>(B, dinv, offs, csr, b4, W5, s5, N);
    // Layer 5: out = A.s5 + b5
    k_agg1<<<(N + 255) / 256, 256, 0, stream>>>(s5, dinv, offs, csr, b5, (float*)d_out, N);
}